// Round 2
// baseline (478.285 us; speedup 1.0000x reference)
//
#include <hip/hip_runtime.h>
#include <hip/hip_bf16.h>
#include <math.h>

#define NROWS  2048
#define NBATCH 2048
#define DIM    64
#define NT     256   // n-tile == blockDim.x (lane <-> n)
#define BT     16    // b-tile per block

__global__ __launch_bounds__(NT, 4) void p2v_main(
    const int*   __restrict__ events,       // [NROWS][NBATCH]
    const int*   __restrict__ col_indices,  // [NBATCH]
    const float* __restrict__ col_times,    // [NBATCH]
    const float* __restrict__ z_rows,       // [8][NROWS][DIM]
    const float* __restrict__ z_cols,       // [COL][DIM]
    const float* __restrict__ gamma_rows,   // [NROWS]
    const float* __restrict__ gamma_cols,   // [COL]
    float*       __restrict__ out)
{
    __shared__ float4 T_lds[BT][2];     // Taylor weights t^o/o!, o=0..7
    __shared__ float  c_lds[BT][DIM];   // gathered z_cols rows
    __shared__ float  gc_lds[BT];
    __shared__ float  wsum_lds[NT / 64];

    const int tid = threadIdx.x;
    const int n   = blockIdx.x * NT + tid;
    const int b0  = blockIdx.y * BT;

    // ---- stage per-b data -------------------------------------------------
    if (tid < BT) {
        const int   b = b0 + tid;
        const float t = col_times[b];
        const float T1 = t;
        const float T2 = T1 * t * 0.5f;
        const float T3 = T2 * t * (1.f / 3.f);
        const float T4 = T3 * t * 0.25f;
        const float T5 = T4 * t * 0.2f;
        const float T6 = T5 * t * (1.f / 6.f);
        const float T7 = T6 * t * (1.f / 7.f);
        T_lds[tid][0] = make_float4(1.f, T1, T2, T3);
        T_lds[tid][1] = make_float4(T4, T5, T6, T7);
        gc_lds[tid]   = gamma_cols[col_indices[b]];
    }
    for (int i = tid; i < BT * DIM; i += NT) {
        const int bl = i >> 6, d = i & (DIM - 1);
        c_lds[bl][d] = z_cols[(size_t)col_indices[b0 + bl] * DIM + d];
    }
    __syncthreads();

    // ---- main: dist^2 accumulation, d-sum stays in-lane -------------------
    float acc[BT];
#pragma unroll
    for (int b = 0; b < BT; ++b) acc[b] = 0.f;

    const float  gr = gamma_rows[n];
    const float* zp = z_rows + (size_t)n * DIM;

#pragma unroll 1
    for (int dc = 0; dc < DIM / 4; ++dc) {
        float4 zv[8];
#pragma unroll
        for (int o = 0; o < 8; ++o)
            zv[o] = *reinterpret_cast<const float4*>(
                zp + (size_t)o * (NROWS * DIM) + dc * 4);
#pragma unroll
        for (int b = 0; b < BT; ++b) {
            const float4 Ta = T_lds[b][0];
            const float4 Tb = T_lds[b][1];
            const float4 cb = *reinterpret_cast<const float4*>(&c_lds[b][dc * 4]);
            float a = acc[b];
#define ZT_COMP(f)                                   \
            {                                        \
                float zt =          zv[0].f * Ta.x;  \
                zt = fmaf(zv[1].f, Ta.y, zt);        \
                zt = fmaf(zv[2].f, Ta.z, zt);        \
                zt = fmaf(zv[3].f, Ta.w, zt);        \
                zt = fmaf(zv[4].f, Tb.x, zt);        \
                zt = fmaf(zv[5].f, Tb.y, zt);        \
                zt = fmaf(zv[6].f, Tb.z, zt);        \
                zt = fmaf(zv[7].f, Tb.w, zt);        \
                const float df = zt - cb.f;          \
                a = fmaf(df, df, a);                 \
            }
            ZT_COMP(x) ZT_COMP(y) ZT_COMP(z) ZT_COMP(w)
#undef ZT_COMP
            acc[b] = a;
        }
    }

    // ---- finish: -log(p_mat) == softplus(s * logit), s = 1-2e -------------
    float lsum = 0.f;
    const int* evp = events + (size_t)n * NBATCH + b0;
#pragma unroll
    for (int bq = 0; bq < BT / 4; ++bq) {
        const int4 ev = *reinterpret_cast<const int4*>(evp + bq * 4);
        const int  evs[4] = {ev.x, ev.y, ev.z, ev.w};
#pragma unroll
        for (int k = 0; k < 4; ++k) {
            const int   b    = bq * 4 + k;
            const float dist = sqrtf(acc[b]);
            const float L    = gr + gc_lds[b] - dist;
            const float x    = (evs[k] != 0) ? -L : L;   // softplus arg
            const float e    = __expf(-fabsf(x));
            lsum += fmaxf(x, 0.f) + __logf(1.f + e);
        }
    }

    // ---- block reduction + one atomic -------------------------------------
#pragma unroll
    for (int off = 32; off > 0; off >>= 1)
        lsum += __shfl_down(lsum, off, 64);
    if ((tid & 63) == 0) wsum_lds[tid >> 6] = lsum;
    __syncthreads();
    if (tid == 0) {
        float s = 0.f;
#pragma unroll
        for (int w = 0; w < NT / 64; ++w) s += wsum_lds[w];
        atomicAdd(out, s);
    }
}

extern "C" void kernel_launch(void* const* d_in, const int* in_sizes, int n_in,
                              void* d_out, int out_size, void* d_ws, size_t ws_size,
                              hipStream_t stream) {
    const int*   events      = (const int*)  d_in[0];
    const int*   col_indices = (const int*)  d_in[1];
    const float* col_times   = (const float*)d_in[2];
    const float* z_rows      = (const float*)d_in[3];
    const float* z_cols      = (const float*)d_in[4];
    const float* gamma_rows  = (const float*)d_in[5];
    const float* gamma_cols  = (const float*)d_in[6];
    float*       out         = (float*)d_out;

    hipMemsetAsync(out, 0, sizeof(float) * out_size, stream);

    dim3 grid(NROWS / NT, NBATCH / BT);
    p2v_main<<<grid, NT, 0, stream>>>(events, col_indices, col_times, z_rows,
                                      z_cols, gamma_rows, gamma_cols, out);
}

// Round 3
// 106.424 us; speedup vs baseline: 4.4941x; 4.4941x over previous
//
#include <hip/hip_runtime.h>
#include <math.h>
#include <stdint.h>

#define NR    2048   // rows (n)
#define NB    2048   // batch (b)
#define DIMD  64
#define KC    576    // 512 cross + 64 gram
#define KSTEP 18     // 576 / 32

typedef __bf16 bf16x8 __attribute__((ext_vector_type(8)));
typedef float  f32x4  __attribute__((ext_vector_type(4)));

typedef const __attribute__((address_space(1))) void* gas_p;
typedef __attribute__((address_space(3))) void*       las_p;

__device__ __forceinline__ unsigned short f2bf(float f) {
    unsigned int u = __float_as_uint(f);
    unsigned int r = u + 0x7FFFu + ((u >> 16) & 1u);
    return (unsigned short)(r >> 16);
}

// ---- prep A: A'[b][k] bf16, cc[b]=||c_b||^2, gcg[b]=gamma_cols[ci[b]] ------
__global__ __launch_bounds__(256) void prep_a(
    const int*   __restrict__ col_indices,
    const float* __restrict__ col_times,
    const float* __restrict__ z_cols,
    const float* __restrict__ gamma_cols,
    unsigned short* __restrict__ Abuf,
    float* __restrict__ cc, float* __restrict__ gcg)
{
    __shared__ float Tl[4][8];
    const int tid = threadIdx.x, w = tid >> 6, lane = tid & 63;
    const int b  = blockIdx.x * 4 + w;
    const float t  = col_times[b];
    const int   ci = col_indices[b];
    if (lane < 8) {                       // T[o] = t^o / o!
        float v = 1.f;
        for (int i = 1; i <= lane; ++i) v = v * t / (float)i;
        Tl[w][lane] = v;
    }
    __syncthreads();
    const float cd = z_cols[ci * DIMD + lane];
    unsigned short* arow = Abuf + (size_t)b * KC;
#pragma unroll
    for (int o = 0; o < 8; ++o)
        arow[o * 64 + lane] = f2bf(-2.f * Tl[w][o] * cd);
    arow[512 + lane] = f2bf(Tl[w][lane >> 3] * Tl[w][lane & 7]);
    float s = cd * cd;
#pragma unroll
    for (int m = 1; m < 64; m <<= 1) s += __shfl_xor(s, m, 64);
    if (lane == 0) { cc[b] = s; gcg[b] = gamma_cols[ci]; }
}

// ---- prep B: B'[n][k] bf16 = [z_rows(o,n,d) | G(n,o1,o2)] ------------------
__global__ __launch_bounds__(256) void prep_b(
    const float* __restrict__ z_rows,
    unsigned short* __restrict__ Bbuf)
{
    const int tid = threadIdx.x, w = tid >> 6, lane = tid & 63;
    const int n = blockIdx.x * 4 + w;
    float z8[8];
#pragma unroll
    for (int o = 0; o < 8; ++o)
        z8[o] = z_rows[o * (NR * DIMD) + n * DIMD + lane];
    unsigned short* brow = Bbuf + (size_t)n * KC;
#pragma unroll
    for (int o = 0; o < 8; ++o)
        brow[o * 64 + lane] = f2bf(z8[o]);
    float myG = 0.f;
#pragma unroll
    for (int o1 = 0; o1 < 8; ++o1)
#pragma unroll
        for (int o2 = o1; o2 < 8; ++o2) {
            float p = z8[o1] * z8[o2];
#pragma unroll
            for (int m = 1; m < 64; m <<= 1) p += __shfl_xor(p, m, 64);
            if (lane == o1 * 8 + o2) myG = p;
            if (o1 != o2 && lane == o2 * 8 + o1) myG = p;
        }
    brow[512 + lane] = f2bf(myG);
}

// ---- main: S = A' * B'^T via MFMA, fused loss epilogue ---------------------
// tile 128(b) x 64(n), BK=32, 4 waves (2x2), wave tile 64x32
__global__ __launch_bounds__(256, 2) void p2v_gemm(
    const unsigned short* __restrict__ Abuf,
    const unsigned short* __restrict__ Bbuf,
    const float* __restrict__ cc,
    const float* __restrict__ gcg,
    const float* __restrict__ gamma_rows,
    const int*   __restrict__ events,
    float*       __restrict__ out)
{
    __shared__ unsigned short As[128 * 32] __attribute__((aligned(16)));
    __shared__ unsigned short Bs[64 * 32]  __attribute__((aligned(16)));
    __shared__ float warr[4];

    const int tid = threadIdx.x, w = tid >> 6, lane = tid & 63;
    const int wm = w >> 1, wn = w & 1;
    const int n0 = blockIdx.x * 64, b0 = blockIdx.y * 128;

    // staging: per wave, 2x A chunks (16 rows x 32k each) + 1x B chunk
    const int lr = lane >> 2, lsl = lane & 3;
    const size_t gA0 = (size_t)(b0 + w * 32 + lr) * KC + lsl * 8;
    const size_t gA1 = gA0 + (size_t)16 * KC;
    const size_t gB0 = (size_t)(n0 + w * 16 + lr) * KC + lsl * 8;
    unsigned short* dstA0 = &As[(w * 32) * 32];
    unsigned short* dstA1 = &As[(w * 32 + 16) * 32];
    unsigned short* dstB0 = &Bs[(w * 16) * 32];

    f32x4 acc[4][2];
#pragma unroll
    for (int mi = 0; mi < 4; ++mi)
#pragma unroll
        for (int ni = 0; ni < 2; ++ni) acc[mi][ni] = (f32x4)(0.f);

    for (int ks = 0; ks < KSTEP; ++ks) {
        const int ko = ks * 32;
        __builtin_amdgcn_global_load_lds((gas_p)(Abuf + gA0 + ko), (las_p)dstA0, 16, 0, 0);
        __builtin_amdgcn_global_load_lds((gas_p)(Abuf + gA1 + ko), (las_p)dstA1, 16, 0, 0);
        __builtin_amdgcn_global_load_lds((gas_p)(Bbuf + gB0 + ko), (las_p)dstB0, 16, 0, 0);
        __syncthreads();
        bf16x8 af[4], bfr[2];
#pragma unroll
        for (int mi = 0; mi < 4; ++mi)
            af[mi] = *reinterpret_cast<const bf16x8*>(
                &As[(wm * 64 + mi * 16 + (lane & 15)) * 32 + (lane >> 4) * 8]);
#pragma unroll
        for (int ni = 0; ni < 2; ++ni)
            bfr[ni] = *reinterpret_cast<const bf16x8*>(
                &Bs[(wn * 32 + ni * 16 + (lane & 15)) * 32 + (lane >> 4) * 8]);
#pragma unroll
        for (int mi = 0; mi < 4; ++mi)
#pragma unroll
            for (int ni = 0; ni < 2; ++ni)
                acc[mi][ni] = __builtin_amdgcn_mfma_f32_16x16x32_bf16(
                    af[mi], bfr[ni], acc[mi][ni], 0, 0, 0);
        __syncthreads();
    }

    // epilogue: dist^2 = S + cc[b]; loss = softplus(+/-logit); reduce
    float ls = 0.f;
#pragma unroll
    for (int ni = 0; ni < 2; ++ni) {
        const int n = n0 + wn * 32 + ni * 16 + (lane & 15);
        const float grn = gamma_rows[n];
        const size_t erow = (size_t)n * NB;
#pragma unroll
        for (int mi = 0; mi < 4; ++mi) {
            const int bb = b0 + wm * 64 + mi * 16 + (lane >> 4) * 4;
            const int4   ev  = *reinterpret_cast<const int4*>(&events[erow + bb]);
            const float4 ccv = *reinterpret_cast<const float4*>(&cc[bb]);
            const float4 gcv = *reinterpret_cast<const float4*>(&gcg[bb]);
#define EPJ(cmp, evv)                                                      \
            {                                                              \
                const float d2   = acc[mi][ni].cmp + ccv.cmp;              \
                const float dist = sqrtf(fmaxf(d2, 0.f));                  \
                const float L    = grn + gcv.cmp - dist;                   \
                const float x    = (evv != 0) ? -L : L;                    \
                ls += fmaxf(x, 0.f) + __logf(1.f + __expf(-fabsf(x)));     \
            }
            EPJ(x, ev.x) EPJ(y, ev.y) EPJ(z, ev.z) EPJ(w, ev.w)
#undef EPJ
        }
    }
#pragma unroll
    for (int m = 1; m < 64; m <<= 1) ls += __shfl_xor(ls, m, 64);
    if (lane == 0) warr[w] = ls;
    __syncthreads();
    if (tid == 0) atomicAdd(out, warr[0] + warr[1] + warr[2] + warr[3]);
}

extern "C" void kernel_launch(void* const* d_in, const int* in_sizes, int n_in,
                              void* d_out, int out_size, void* d_ws, size_t ws_size,
                              hipStream_t stream) {
    const int*   events      = (const int*)  d_in[0];
    const int*   col_indices = (const int*)  d_in[1];
    const float* col_times   = (const float*)d_in[2];
    const float* z_rows      = (const float*)d_in[3];
    const float* z_cols      = (const float*)d_in[4];
    const float* gamma_rows  = (const float*)d_in[5];
    const float* gamma_cols  = (const float*)d_in[6];
    float*       out         = (float*)d_out;

    unsigned short* Abuf = (unsigned short*)d_ws;                // 2048*576 bf16
    unsigned short* Bbuf = Abuf + (size_t)NB * KC;               // 2048*576 bf16
    float*          cc   = (float*)(Bbuf + (size_t)NR * KC);     // 2048 f32
    float*          gcg  = cc + NB;                              // 2048 f32

    hipMemsetAsync(out, 0, sizeof(float) * out_size, stream);
    prep_a<<<NB / 4, 256, 0, stream>>>(col_indices, col_times, z_cols, gamma_cols,
                                       Abuf, cc, gcg);
    prep_b<<<NR / 4, 256, 0, stream>>>(z_rows, Bbuf);
    dim3 grid(NR / 64, NB / 128);
    p2v_gemm<<<grid, 256, 0, stream>>>(Abuf, Bbuf, cc, gcg, gamma_rows, events, out);
}

// Round 4
// 100.215 us; speedup vs baseline: 4.7726x; 1.0620x over previous
//
#include <hip/hip_runtime.h>
#include <math.h>
#include <stdint.h>

#define NR    2048   // rows (n)
#define NB    2048   // batch (b)
#define DIMD  64
#define KC    576    // 512 cross + 64 gram
#define BK    64
#define KSTEP 9      // 576 / 64

typedef __bf16 bf16x8 __attribute__((ext_vector_type(8)));
typedef float  f32x4  __attribute__((ext_vector_type(4)));

typedef const __attribute__((address_space(1))) void* gas_p;
typedef __attribute__((address_space(3))) void*       las_p;

__device__ __forceinline__ unsigned short f2bf(float f) {
    unsigned int u = __float_as_uint(f);
    unsigned int r = u + 0x7FFFu + ((u >> 16) & 1u);
    return (unsigned short)(r >> 16);
}

// ---- fused prep: blocks [0,512) build A'/cc/gcg, [512,1024) build B' -------
__global__ __launch_bounds__(256) void prep_all(
    const int*   __restrict__ col_indices,
    const float* __restrict__ col_times,
    const float* __restrict__ z_cols,
    const float* __restrict__ gamma_cols,
    const float* __restrict__ z_rows,
    unsigned short* __restrict__ Abuf,
    unsigned short* __restrict__ Bbuf,
    float* __restrict__ cc, float* __restrict__ gcg)
{
    const int tid = threadIdx.x, w = tid >> 6, lane = tid & 63;
    if (blockIdx.x < 512) {
        __shared__ float Tl[4][8];
        const int b  = blockIdx.x * 4 + w;
        const float t  = col_times[b];
        const int   ci = col_indices[b];
        if (lane < 8) {                       // T[o] = t^o / o!
            float v = 1.f;
            for (int i = 1; i <= lane; ++i) v = v * t / (float)i;
            Tl[w][lane] = v;
        }
        __syncthreads();
        const float cd = z_cols[ci * DIMD + lane];
        unsigned short* arow = Abuf + (size_t)b * KC;
#pragma unroll
        for (int o = 0; o < 8; ++o)
            arow[o * 64 + lane] = f2bf(-2.f * Tl[w][o] * cd);
        arow[512 + lane] = f2bf(Tl[w][lane >> 3] * Tl[w][lane & 7]);
        float s = cd * cd;
#pragma unroll
        for (int m = 1; m < 64; m <<= 1) s += __shfl_xor(s, m, 64);
        if (lane == 0) { cc[b] = s; gcg[b] = gamma_cols[ci]; }
    } else {
        const int n = (blockIdx.x - 512) * 4 + w;
        float z8[8];
#pragma unroll
        for (int o = 0; o < 8; ++o)
            z8[o] = z_rows[o * (NR * DIMD) + n * DIMD + lane];
        unsigned short* brow = Bbuf + (size_t)n * KC;
#pragma unroll
        for (int o = 0; o < 8; ++o)
            brow[o * 64 + lane] = f2bf(z8[o]);
        float myG = 0.f;
#pragma unroll
        for (int o1 = 0; o1 < 8; ++o1)
#pragma unroll
            for (int o2 = o1; o2 < 8; ++o2) {
                float p = z8[o1] * z8[o2];
#pragma unroll
                for (int m = 1; m < 64; m <<= 1) p += __shfl_xor(p, m, 64);
                if (lane == o1 * 8 + o2) myG = p;
                if (o1 != o2 && lane == o2 * 8 + o1) myG = p;
            }
        brow[512 + lane] = f2bf(myG);
    }
}

// ---- main: S = A' * B'^T via MFMA, fused loss epilogue ---------------------
// tile 128(b) x 64(n), BK=64, 4 waves (2x2), wave tile 64x32
// LDS rows are 128B: XOR-swizzle slot' = slot ^ (row&7) (pre-swizzled global
// source + swizzled read, linear gload_lds dest) -> conflict-free ds_read_b128
__global__ __launch_bounds__(256, 2) void p2v_gemm(
    const unsigned short* __restrict__ Abuf,
    const unsigned short* __restrict__ Bbuf,
    const float* __restrict__ cc,
    const float* __restrict__ gcg,
    const float* __restrict__ gamma_rows,
    const int*   __restrict__ events,
    float*       __restrict__ out)
{
    __shared__ unsigned short As[128 * BK] __attribute__((aligned(16))); // 16KB
    __shared__ unsigned short Bs[64 * BK]  __attribute__((aligned(16))); //  8KB
    __shared__ float warr[4];

    const int tid = threadIdx.x, w = tid >> 6, lane = tid & 63;
    const int wm = w >> 1, wn = w & 1;
    const int n0 = blockIdx.x * 64, b0 = blockIdx.y * 128;

    // staging geometry: each gload_lds instr moves 8 rows x 128B (1KB).
    // lane -> row_local = lane>>3, k-chunk (16B) = (lane&7) ^ (lane>>3)
    const int lr8 = lane >> 3;
    const int cx  = (lane & 7) ^ lr8;            // swizzled source chunk
    const size_t gA = (size_t)(b0 + w * 32 + lr8) * KC + cx * 8;
    const size_t gB = (size_t)(n0 + w * 16 + lr8) * KC + cx * 8;
    unsigned short* dA = &As[(w * 32) * BK];     // + i*512 elements per instr
    unsigned short* dB = &Bs[(w * 16) * BK];

    f32x4 acc[4][2];
#pragma unroll
    for (int mi = 0; mi < 4; ++mi)
#pragma unroll
        for (int ni = 0; ni < 2; ++ni) acc[mi][ni] = (f32x4)(0.f);

    for (int ks = 0; ks < KSTEP; ++ks) {
        const int ko = ks * BK;
#pragma unroll
        for (int i = 0; i < 4; ++i)
            __builtin_amdgcn_global_load_lds((gas_p)(Abuf + gA + (size_t)(i * 8) * KC + ko),
                                             (las_p)(dA + i * 512), 16, 0, 0);
#pragma unroll
        for (int i = 0; i < 2; ++i)
            __builtin_amdgcn_global_load_lds((gas_p)(Bbuf + gB + (size_t)(i * 8) * KC + ko),
                                             (las_p)(dB + i * 512), 16, 0, 0);
        __syncthreads();
#pragma unroll
        for (int kk = 0; kk < 2; ++kk) {
            const int slot = (kk * 4 + (lane >> 4)) ^ (lane & 7);  // ^ (row&7)
            bf16x8 af[4], bfr[2];
#pragma unroll
            for (int mi = 0; mi < 4; ++mi)
                af[mi] = *reinterpret_cast<const bf16x8*>(
                    &As[(wm * 64 + mi * 16 + (lane & 15)) * BK + slot * 8]);
#pragma unroll
            for (int ni = 0; ni < 2; ++ni)
                bfr[ni] = *reinterpret_cast<const bf16x8*>(
                    &Bs[(wn * 32 + ni * 16 + (lane & 15)) * BK + slot * 8]);
#pragma unroll
            for (int mi = 0; mi < 4; ++mi)
#pragma unroll
                for (int ni = 0; ni < 2; ++ni)
                    acc[mi][ni] = __builtin_amdgcn_mfma_f32_16x16x32_bf16(
                        af[mi], bfr[ni], acc[mi][ni], 0, 0, 0);
        }
        __syncthreads();
    }

    // epilogue: dist^2 = S + cc[b]; loss = softplus(+/-logit); reduce
    float ls = 0.f;
#pragma unroll
    for (int ni = 0; ni < 2; ++ni) {
        const int n = n0 + wn * 32 + ni * 16 + (lane & 15);
        const float grn = gamma_rows[n];
        const size_t erow = (size_t)n * NB;
#pragma unroll
        for (int mi = 0; mi < 4; ++mi) {
            const int bb = b0 + wm * 64 + mi * 16 + (lane >> 4) * 4;
            const int4   ev  = *reinterpret_cast<const int4*>(&events[erow + bb]);
            const float4 ccv = *reinterpret_cast<const float4*>(&cc[bb]);
            const float4 gcv = *reinterpret_cast<const float4*>(&gcg[bb]);
#define EPJ(cmp, evv)                                                      \
            {                                                              \
                const float d2   = acc[mi][ni].cmp + ccv.cmp;              \
                const float dist = sqrtf(fmaxf(d2, 0.f));                  \
                const float L    = grn + gcv.cmp - dist;                   \
                const float x    = (evv != 0) ? -L : L;                    \
                ls += fmaxf(x, 0.f) + __logf(1.f + __expf(-fabsf(x)));     \
            }
            EPJ(x, ev.x) EPJ(y, ev.y) EPJ(z, ev.z) EPJ(w, ev.w)
#undef EPJ
        }
    }
#pragma unroll
    for (int m = 1; m < 64; m <<= 1) ls += __shfl_xor(ls, m, 64);
    if (lane == 0) warr[w] = ls;
    __syncthreads();
    if (tid == 0) atomicAdd(out, warr[0] + warr[1] + warr[2] + warr[3]);
}

extern "C" void kernel_launch(void* const* d_in, const int* in_sizes, int n_in,
                              void* d_out, int out_size, void* d_ws, size_t ws_size,
                              hipStream_t stream) {
    const int*   events      = (const int*)  d_in[0];
    const int*   col_indices = (const int*)  d_in[1];
    const float* col_times   = (const float*)d_in[2];
    const float* z_rows      = (const float*)d_in[3];
    const float* z_cols      = (const float*)d_in[4];
    const float* gamma_rows  = (const float*)d_in[5];
    const float* gamma_cols  = (const float*)d_in[6];
    float*       out         = (float*)d_out;

    unsigned short* Abuf = (unsigned short*)d_ws;                // 2048*576 bf16
    unsigned short* Bbuf = Abuf + (size_t)NB * KC;               // 2048*576 bf16
    float*          cc   = (float*)(Bbuf + (size_t)NR * KC);     // 2048 f32
    float*          gcg  = cc + NB;                              // 2048 f32

    hipMemsetAsync(out, 0, sizeof(float) * out_size, stream);
    prep_all<<<1024, 256, 0, stream>>>(col_indices, col_times, z_cols, gamma_cols,
                                       z_rows, Abuf, Bbuf, cc, gcg);
    dim3 grid(NR / 64, NB / 128);
    p2v_gemm<<<grid, 256, 0, stream>>>(Abuf, Bbuf, cc, gcg, gamma_rows, events, out);
}

// Round 5
// 99.727 us; speedup vs baseline: 4.7959x; 1.0049x over previous
//
#include <hip/hip_runtime.h>
#include <math.h>
#include <stdint.h>

#define NR    2048   // rows (n)
#define NB    2048   // batch (b)
#define DIMD  64
#define KC    576    // 512 cross + 64 gram
#define BK    64
#define KSTEP 9      // 576 / 64

typedef __bf16 bf16x8 __attribute__((ext_vector_type(8)));
typedef float  f32x4  __attribute__((ext_vector_type(4)));

typedef const __attribute__((address_space(1))) void* gas_p;
typedef __attribute__((address_space(3))) void*       las_p;

__device__ __forceinline__ unsigned short f2bf(float f) {
    unsigned int u = __float_as_uint(f);
    unsigned int r = u + 0x7FFFu + ((u >> 16) & 1u);
    return (unsigned short)(r >> 16);
}

// ---- fused prep: blocks [0,512) build A'/cc/gcg, [512,1024) build B' -------
// block 0 also zeroes d_out (stream order guarantees this precedes the GEMM).
__global__ __launch_bounds__(256) void prep_all(
    const int*   __restrict__ col_indices,
    const float* __restrict__ col_times,
    const float* __restrict__ z_cols,
    const float* __restrict__ gamma_cols,
    const float* __restrict__ z_rows,
    unsigned short* __restrict__ Abuf,
    unsigned short* __restrict__ Bbuf,
    float* __restrict__ cc, float* __restrict__ gcg,
    float* __restrict__ out)
{
    const int tid = threadIdx.x, w = tid >> 6, lane = tid & 63;
    if (blockIdx.x == 0 && tid == 0) *out = 0.f;
    if (blockIdx.x < 512) {
        __shared__ float Tl[4][8];
        const int b  = blockIdx.x * 4 + w;
        const float t  = col_times[b];
        const int   ci = col_indices[b];
        if (lane < 8) {                       // T[o] = t^o / o!
            float v = 1.f;
            for (int i = 1; i <= lane; ++i) v = v * t / (float)i;
            Tl[w][lane] = v;
        }
        __syncthreads();
        const float cd = z_cols[ci * DIMD + lane];
        unsigned short* arow = Abuf + (size_t)b * KC;
#pragma unroll
        for (int o = 0; o < 8; ++o)
            arow[o * 64 + lane] = f2bf(-2.f * Tl[w][o] * cd);
        arow[512 + lane] = f2bf(Tl[w][lane >> 3] * Tl[w][lane & 7]);
        float s = cd * cd;
#pragma unroll
        for (int m = 1; m < 64; m <<= 1) s += __shfl_xor(s, m, 64);
        if (lane == 0) { cc[b] = s; gcg[b] = gamma_cols[ci]; }
    } else {
        const int n = (blockIdx.x - 512) * 4 + w;
        float z8[8];
#pragma unroll
        for (int o = 0; o < 8; ++o)
            z8[o] = z_rows[o * (NR * DIMD) + n * DIMD + lane];
        unsigned short* brow = Bbuf + (size_t)n * KC;
#pragma unroll
        for (int o = 0; o < 8; ++o)
            brow[o * 64 + lane] = f2bf(z8[o]);
        float myG = 0.f;
#pragma unroll
        for (int o1 = 0; o1 < 8; ++o1)
#pragma unroll
            for (int o2 = o1; o2 < 8; ++o2) {
                float p = z8[o1] * z8[o2];
#pragma unroll
                for (int m = 1; m < 64; m <<= 1) p += __shfl_xor(p, m, 64);
                if (lane == o1 * 8 + o2) myG = p;
                if (o1 != o2 && lane == o2 * 8 + o1) myG = p;
            }
        brow[512 + lane] = f2bf(myG);
    }
}

// ---- main: S = A' * B'^T via MFMA, double-buffered 2-phase, fused loss -----
// tile 128(b) x 64(n), BK=64, 4 waves (2x2), wave tile 64x32
// LDS rows 128B: XOR swizzle (pre-swizzled global source + swizzled read,
// linear gload_lds dest). dbuf: STAGE(next) issued before compute(cur),
// single __syncthreads (vmcnt0+lgkmcnt0 drain) per K-step at loop bottom.
__global__ __launch_bounds__(256, 2) void p2v_gemm(
    const unsigned short* __restrict__ Abuf,
    const unsigned short* __restrict__ Bbuf,
    const float* __restrict__ cc,
    const float* __restrict__ gcg,
    const float* __restrict__ gamma_rows,
    const int*   __restrict__ events,
    float*       __restrict__ out)
{
    __shared__ unsigned short As[2][128 * BK] __attribute__((aligned(16))); // 32KB
    __shared__ unsigned short Bs[2][64 * BK]  __attribute__((aligned(16))); // 16KB
    __shared__ float warr[4];

    const int tid = threadIdx.x, w = tid >> 6, lane = tid & 63;
    const int wm = w >> 1, wn = w & 1;
    const int n0 = blockIdx.x * 64, b0 = blockIdx.y * 128;

    // staging geometry: each gload_lds moves 8 rows x 128B (1KB).
    // lane -> row_local = lane>>3, source 16B chunk = (lane&7) ^ (row&7)
    const int lr8 = lane >> 3;
    const int cx  = (lane & 7) ^ lr8;
    const size_t gA = (size_t)(b0 + w * 32 + lr8) * KC + cx * 8;
    const size_t gB = (size_t)(n0 + w * 16 + lr8) * KC + cx * 8;
    const int dAo = (w * 32) * BK;   // element offsets within a buffer
    const int dBo = (w * 16) * BK;

    f32x4 acc[4][2];
#pragma unroll
    for (int mi = 0; mi < 4; ++mi)
#pragma unroll
        for (int ni = 0; ni < 2; ++ni) acc[mi][ni] = (f32x4)(0.f);

#define STAGE(buf, ks)                                                         \
    {                                                                          \
        const int ko_ = (ks) * BK;                                             \
        _Pragma("unroll")                                                      \
        for (int i = 0; i < 4; ++i)                                            \
            __builtin_amdgcn_global_load_lds(                                  \
                (gas_p)(Abuf + gA + (size_t)(i * 8) * KC + ko_),               \
                (las_p)&As[buf][dAo + i * 512], 16, 0, 0);                     \
        _Pragma("unroll")                                                      \
        for (int i = 0; i < 2; ++i)                                            \
            __builtin_amdgcn_global_load_lds(                                  \
                (gas_p)(Bbuf + gB + (size_t)(i * 8) * KC + ko_),               \
                (las_p)&Bs[buf][dBo + i * 512], 16, 0, 0);                     \
    }

    STAGE(0, 0);
    __syncthreads();

#pragma unroll
    for (int ks = 0; ks < KSTEP; ++ks) {
        const int cur = ks & 1;
        if (ks + 1 < KSTEP) STAGE(cur ^ 1, ks + 1);
#pragma unroll
        for (int kk = 0; kk < 2; ++kk) {
            const int slot = (kk * 4 + (lane >> 4)) ^ (lane & 7);  // ^ (row&7)
            bf16x8 af[4], bfr[2];
#pragma unroll
            for (int mi = 0; mi < 4; ++mi)
                af[mi] = *reinterpret_cast<const bf16x8*>(
                    &As[cur][(wm * 64 + mi * 16 + (lane & 15)) * BK + slot * 8]);
#pragma unroll
            for (int ni = 0; ni < 2; ++ni)
                bfr[ni] = *reinterpret_cast<const bf16x8*>(
                    &Bs[cur][(wn * 32 + ni * 16 + (lane & 15)) * BK + slot * 8]);
#pragma unroll
            for (int mi = 0; mi < 4; ++mi)
#pragma unroll
                for (int ni = 0; ni < 2; ++ni)
                    acc[mi][ni] = __builtin_amdgcn_mfma_f32_16x16x32_bf16(
                        af[mi], bfr[ni], acc[mi][ni], 0, 0, 0);
        }
        __syncthreads();
    }
#undef STAGE

    // epilogue: dist^2 = S + cc[b]; loss = softplus(+/-logit); reduce
    float ls = 0.f;
#pragma unroll
    for (int ni = 0; ni < 2; ++ni) {
        const int n = n0 + wn * 32 + ni * 16 + (lane & 15);
        const float grn = gamma_rows[n];
        const size_t erow = (size_t)n * NB;
#pragma unroll
        for (int mi = 0; mi < 4; ++mi) {
            const int bb = b0 + wm * 64 + mi * 16 + (lane >> 4) * 4;
            const int4   ev  = *reinterpret_cast<const int4*>(&events[erow + bb]);
            const float4 ccv = *reinterpret_cast<const float4*>(&cc[bb]);
            const float4 gcv = *reinterpret_cast<const float4*>(&gcg[bb]);
#define EPJ(cmp, evv)                                                      \
            {                                                              \
                const float d2   = acc[mi][ni].cmp + ccv.cmp;              \
                const float dist = sqrtf(fmaxf(d2, 0.f));                  \
                const float L    = grn + gcv.cmp - dist;                   \
                const float x    = (evv != 0) ? -L : L;                    \
                ls += fmaxf(x, 0.f) + __logf(1.f + __expf(-fabsf(x)));     \
            }
            EPJ(x, ev.x) EPJ(y, ev.y) EPJ(z, ev.z) EPJ(w, ev.w)
#undef EPJ
        }
    }
#pragma unroll
    for (int m = 1; m < 64; m <<= 1) ls += __shfl_xor(ls, m, 64);
    if (lane == 0) warr[w] = ls;
    __syncthreads();
    if (tid == 0) atomicAdd(out, warr[0] + warr[1] + warr[2] + warr[3]);
}

extern "C" void kernel_launch(void* const* d_in, const int* in_sizes, int n_in,
                              void* d_out, int out_size, void* d_ws, size_t ws_size,
                              hipStream_t stream) {
    const int*   events      = (const int*)  d_in[0];
    const int*   col_indices = (const int*)  d_in[1];
    const float* col_times   = (const float*)d_in[2];
    const float* z_rows      = (const float*)d_in[3];
    const float* z_cols      = (const float*)d_in[4];
    const float* gamma_rows  = (const float*)d_in[5];
    const float* gamma_cols  = (const float*)d_in[6];
    float*       out         = (float*)d_out;

    unsigned short* Abuf = (unsigned short*)d_ws;                // 2048*576 bf16
    unsigned short* Bbuf = Abuf + (size_t)NB * KC;               // 2048*576 bf16
    float*          cc   = (float*)(Bbuf + (size_t)NR * KC);     // 2048 f32
    float*          gcg  = cc + NB;                              // 2048 f32

    prep_all<<<1024, 256, 0, stream>>>(col_indices, col_times, z_cols, gamma_cols,
                                       z_rows, Abuf, Bbuf, cc, gcg, out);
    dim3 grid(NR / 64, NB / 128);
    p2v_gemm<<<grid, 256, 0, stream>>>(Abuf, Bbuf, cc, gcg, gamma_rows, events, out);
}